// Round 4
// baseline (146.112 us; speedup 1.0000x reference)
//
#include <hip/hip_runtime.h>
#include <hip/hip_cooperative_groups.h>

namespace cg = cooperative_groups;

// y[b,f,d] = relu( prefixW[d, fi] + frac * W[d, fi] + bias[d] ),
//   fi = floor(x+1000), frac = (x+1000) - fi.   B=128, F=512, D=128, NB=2000.
//
// Single cooperative kernel, 512 blocks x 256 threads (2 blocks/CU, fully
// co-resident). Three phases separated by grid.sync():
//   1a (blocks 0..127):  per-d chunk sums (250 chunks x 8 bins) + block scan
//                        -> Pex[250][128]
//   1b (blocks 0..249):  emit Ct[n][d] (= prefix + bias) and Wt[n][d] = W[d,n],
//                        coalesced across d; 256 thr = 128 d x 2 bin-halves
//   2  (all 512 blocks): out[pair,d] = relu(fma(frac, Wt[fi][d], Ct[fi][d])),
//                        128 pairs/block, nontemporal f4 stores.
// Row NB=2000 of the tables holds the full sum (pos==2000.0 rounding edge).

#define NB    2000
#define DD    128
#define CHUNK 8
#define CH    250            // CH*CHUNK == NB
#define NPAIR (128 * 512)
#define GRID  512

typedef float f4 __attribute__((ext_vector_type(4)));

__global__ __launch_bounds__(256, 2) void mega_kernel(const float* __restrict__ x,
                                                      const float* __restrict__ W,
                                                      const float* __restrict__ bias,
                                                      float* __restrict__ Ct,
                                                      float* __restrict__ Wt,
                                                      float* __restrict__ Pex,
                                                      float* __restrict__ out) {
    cg::grid_group grid = cg::this_grid();
    __shared__ float wtot[4];

    const int tid = threadIdx.x;
    const int bid = blockIdx.x;

    // ---------------- Phase 1a: chunk sums + block scan (blocks 0..127) ----
    if (bid < DD) {
        const int d = bid;
        const int t = tid;                 // chunk id, 0..249 active
        float s = 0.f;
        if (t < CH) {
            const f4* p = (const f4*)(W + (size_t)d * NB + t * CHUNK);
            f4 a = p[0], b = p[1];
            s = ((a.x + a.y) + (a.z + a.w)) + ((b.x + b.y) + (b.z + b.w));
        }
        float inc = s;
        #pragma unroll
        for (int off = 1; off < 64; off <<= 1) {
            float o = __shfl_up(inc, off);
            if ((t & 63) >= off) inc += o;
        }
        const int w = t >> 6, l = t & 63;
        if (l == 63) wtot[w] = inc;
        __syncthreads();
        float add = 0.f;
        #pragma unroll
        for (int k = 0; k < 3; k++)
            if (k < w) add += wtot[k];
        if (t < CH) Pex[t * DD + d] = (inc - s) + add;
    }

    grid.sync();

    // ---------------- Phase 1b: emit tables (blocks 0..249) ----------------
    if (bid < CH) {
        const int c = bid;
        const int d = tid & 127;
        const int h = tid >> 7;            // 0: bins 0..3, 1: bins 4..7
        float run = Pex[c * DD + d] + bias[d];
        const float* p = W + (size_t)d * NB + c * CHUNK;
        f4 a  = *(const f4*)(p);
        f4 b  = *(const f4*)(p + 4);
        if (h) run += ((a.x + a.y) + (a.z + a.w));
        f4 v = h ? b : a;
        const float wv[4] = {v.x, v.y, v.z, v.w};
        const int nbase = c * CHUNK + h * 4;
        #pragma unroll
        for (int i = 0; i < 4; i++) {
            Ct[(size_t)(nbase + i) * DD + d] = run;   // 512B contiguous per i
            Wt[(size_t)(nbase + i) * DD + d] = wv[i];
            run += wv[i];
        }
        if (c == CH - 1 && h == 1) {       // row NB: full prefix (edge case)
            Ct[(size_t)NB * DD + d] = run;
            Wt[(size_t)NB * DD + d] = 0.f;
        }
    }

    grid.sync();

    // ---------------- Phase 2: eval (all blocks) ---------------------------
    {
        const int lane = tid & 31;         // 32 lanes x f4 cover d=0..127
        const int slot = tid >> 5;         // 0..7
        const int d4   = lane * 4;
        const int pbase = bid * (NPAIR / GRID);   // 128 pairs per block

        #pragma unroll 4
        for (int h = 0; h < (NPAIR / GRID) / 8; h++) {
            const int pair = pbase + h * 8 + slot;
            const float pos = x[pair] + 1000.0f;
            const float fl  = floorf(pos);
            float frac = pos - fl;
            int fi = (int)fl;
            if (fi >= NB) { fi = NB; frac = 0.f; }
            if (fi < 0)   { fi = 0;  frac = 0.f; }

            const f4 c = *(const f4*)(Ct + (size_t)fi * DD + d4);
            const f4 w = *(const f4*)(Wt + (size_t)fi * DD + d4);

            f4 r;
            r.x = fmaxf(fmaf(frac, w.x, c.x), 0.f);
            r.y = fmaxf(fmaf(frac, w.y, c.y), 0.f);
            r.z = fmaxf(fmaf(frac, w.z, c.z), 0.f);
            r.w = fmaxf(fmaf(frac, w.w, c.w), 0.f);

            __builtin_nontemporal_store(r, (f4*)(out + (size_t)pair * DD + d4));
        }
    }
}

extern "C" void kernel_launch(void* const* d_in, const int* in_sizes, int n_in,
                              void* d_out, int out_size, void* d_ws, size_t ws_size,
                              hipStream_t stream) {
    const float* x    = (const float*)d_in[0];   // [128, 512]
    const float* W    = (const float*)d_in[1];   // [128, 2000]
    const float* bias = (const float*)d_in[2];   // [128]
    float* out = (float*)d_out;                  // [128, 512, 128] f32

    float* Ct  = (float*)d_ws;                        // (NB+1) x 128
    float* Wt  = Ct + (size_t)(NB + 1) * DD;          // (NB+1) x 128
    float* Pex = Wt + (size_t)(NB + 1) * DD;          // CH x 128

    void* args[] = {(void*)&x, (void*)&W, (void*)&bias,
                    (void*)&Ct, (void*)&Wt, (void*)&Pex, (void*)&out};
    hipLaunchCooperativeKernel((const void*)mega_kernel, dim3(GRID), dim3(256),
                               args, 0, stream);
}

// Round 5
// 21.192 us; speedup vs baseline: 6.8948x; 6.8948x over previous
//
#include <hip/hip_runtime.h>

// y[b,f,d] = relu( prefixW[d, fi] + frac * W[d, fi] + bias[d] ),
//   fi = floor(x+1000), frac = (x+1000) - fi.   B=128, F=512, D=128, NB=2000.
//
// Interleaved table T[n][d] = float2{ Ct, Wt }:
//   Ct = sum_{k<n} W[d,k] + bias[d]  (bias folded),  Wt = W[d,n].
// Row NB=2000 holds the full sum (pos==2000.0 float-rounding edge), Wt=0.
//
// K1 build: 128 blocks (one per d) x 256 thr. Thread c sums its 8-bin chunk,
//           block scan (wave shfl + LDS wave totals, ONE __syncthreads),
//           then emits its chunk's float2 entries (8B stores, d-column).
//           No cross-block dependency -> single kernel, no grid sync.
// K2 eval : 4096 blocks x 256 thr, 16 pairs/block; per pair 32 lanes x 32B
//           contiguous table read; nontemporal f4 out stores.

#define NB    2000
#define DD    128
#define CHUNK 8
#define CH    250            // CH*CHUNK == NB
#define NPAIR (128 * 512)

typedef float f4 __attribute__((ext_vector_type(4)));
typedef float f2 __attribute__((ext_vector_type(2)));

// ---------------------------------------------------------------------------
__global__ __launch_bounds__(256) void build_kernel(const float* __restrict__ W,
                                                    const float* __restrict__ bias,
                                                    f2* __restrict__ T) {
    const int d = blockIdx.x;      // 0..127
    const int t = threadIdx.x;     // chunk id; 0..249 active

    f4 a = {0.f, 0.f, 0.f, 0.f}, b = {0.f, 0.f, 0.f, 0.f};
    float s = 0.f;
    if (t < CH) {
        const f4* p = (const f4*)(W + (size_t)d * NB + t * CHUNK);
        a = p[0]; b = p[1];
        s = ((a.x + a.y) + (a.z + a.w)) + ((b.x + b.y) + (b.z + b.w));
    }

    // wave-level inclusive scan
    float inc = s;
    #pragma unroll
    for (int off = 1; off < 64; off <<= 1) {
        float o = __shfl_up(inc, off);
        if ((t & 63) >= off) inc += o;
    }
    // block-level: totals of preceding waves
    __shared__ float wtot[4];
    const int w = t >> 6, l = t & 63;
    if (l == 63) wtot[w] = inc;
    __syncthreads();
    float add = 0.f;
    #pragma unroll
    for (int k = 0; k < 3; k++)
        if (k < w) add += wtot[k];

    if (t < CH) {
        float run = (inc - s) + add + bias[d];
        const float wv[CHUNK] = {a.x, a.y, a.z, a.w, b.x, b.y, b.z, b.w};
        const int nbase = t * CHUNK;
        #pragma unroll
        for (int i = 0; i < CHUNK; i++) {
            f2 e; e.x = run; e.y = wv[i];
            T[(size_t)(nbase + i) * DD + d] = e;     // 8B store
            run += wv[i];
        }
        if (t == CH - 1) {          // row NB: full prefix (rounding edge)
            f2 e; e.x = run; e.y = 0.f;
            T[(size_t)NB * DD + d] = e;
        }
    }
}

// ---------------------------------------------------------------------------
__global__ __launch_bounds__(256) void eval_kernel(const float* __restrict__ x,
                                                   const f4* __restrict__ T,
                                                   float* __restrict__ out) {
    const int tid  = threadIdx.x;
    const int lane = tid & 31;      // 32 lanes x 4 d's cover d=0..127
    const int slot = tid >> 5;      // 0..7
    const int base = blockIdx.x * 16;

    #pragma unroll
    for (int h = 0; h < 2; h++) {
        const int pair = base + slot + h * 8;
        const float pos = x[pair] + 1000.0f;
        const float fl  = floorf(pos);
        float frac = pos - fl;
        int fi = (int)fl;
        if (fi >= NB) { fi = NB; frac = 0.f; }
        if (fi < 0)   { fi = 0;  frac = 0.f; }

        // T as f4: element k = {Ct[2k], Wt[2k], Ct[2k+1], Wt[2k+1]}
        const f4* tp = T + ((size_t)fi * DD + lane * 4) / 2;
        const f4 cw0 = tp[0];       // d4+0, d4+1
        const f4 cw1 = tp[1];       // d4+2, d4+3

        f4 r;
        r.x = fmaxf(fmaf(frac, cw0.y, cw0.x), 0.f);
        r.y = fmaxf(fmaf(frac, cw0.w, cw0.z), 0.f);
        r.z = fmaxf(fmaf(frac, cw1.y, cw1.x), 0.f);
        r.w = fmaxf(fmaf(frac, cw1.w, cw1.z), 0.f);

        __builtin_nontemporal_store(r, (f4*)(out + (size_t)pair * DD + lane * 4));
    }
}

extern "C" void kernel_launch(void* const* d_in, const int* in_sizes, int n_in,
                              void* d_out, int out_size, void* d_ws, size_t ws_size,
                              hipStream_t stream) {
    const float* x    = (const float*)d_in[0];   // [128, 512]
    const float* W    = (const float*)d_in[1];   // [128, 2000]
    const float* bias = (const float*)d_in[2];   // [128]
    float* out = (float*)d_out;                  // [128, 512, 128] f32

    f2* T = (f2*)d_ws;                           // (NB+1) x 128 x float2 ~2.05MB

    hipLaunchKernelGGL(build_kernel, dim3(DD), dim3(256), 0, stream, W, bias, T);
    hipLaunchKernelGGL(eval_kernel, dim3(NPAIR / 16), dim3(256), 0, stream,
                       x, (const f4*)T, out);
}

// Round 6
// 17.746 us; speedup vs baseline: 8.2335x; 1.1941x over previous
//
#include <hip/hip_runtime.h>

// y[b,f,d] = relu( prefixW[d, fi] + frac * W[d, fi] + bias[d] ),
//   fi = floor(x+1000), frac = (x+1000) - fi.   B=128, F=512, D=128, NB=2000.
//
// Packed bf16 table T[n][d] : uint32 = { bf16(Wt) << 16 | bf16(Ct) }
//   Ct = sum_{k<n} W[d,k] + bias[d]  (bias folded),  Wt = W[d,n].
// Row NB=2000 holds the full sum (pos==2000.0 float-rounding edge), Wt=0.
// Table is 1 MB -> stays L2-resident per XCD; one 16B gather per lane per
// pair covers 4 d's (512B per row).
//
// K1 build: 128 blocks (one per d) x 256 thr; thread c sums its 8-bin chunk,
//           block scan (wave shfl + LDS wave totals), emits packed entries.
// K2 eval : 4096 blocks x 256 thr, 16 pairs/block; 1 gather + unpack;
//           nontemporal f4 out stores (write-once output).

#define NB    2000
#define DD    128
#define CHUNK 8
#define CH    250            // CH*CHUNK == NB
#define NPAIR (128 * 512)

typedef float f4 __attribute__((ext_vector_type(4)));
typedef unsigned int u32;
typedef u32 u4 __attribute__((ext_vector_type(4)));

__device__ __forceinline__ u32 pack_bf16(float ct, float wt) {
    u32 cb = (__float_as_uint(ct) + 0x8000u) >> 16;          // RN bf16, low
    u32 wb = (__float_as_uint(wt) + 0x8000u) & 0xffff0000u;  // RN bf16, high
    return wb | cb;
}

// ---------------------------------------------------------------------------
__global__ __launch_bounds__(256) void build_kernel(const float* __restrict__ W,
                                                    const float* __restrict__ bias,
                                                    u32* __restrict__ T) {
    const int d = blockIdx.x;      // 0..127
    const int t = threadIdx.x;     // chunk id; 0..249 active

    f4 a = {0.f, 0.f, 0.f, 0.f}, b = {0.f, 0.f, 0.f, 0.f};
    float s = 0.f;
    if (t < CH) {
        const f4* p = (const f4*)(W + (size_t)d * NB + t * CHUNK);
        a = p[0]; b = p[1];
        s = ((a.x + a.y) + (a.z + a.w)) + ((b.x + b.y) + (b.z + b.w));
    }

    // wave-level inclusive scan
    float inc = s;
    #pragma unroll
    for (int off = 1; off < 64; off <<= 1) {
        float o = __shfl_up(inc, off);
        if ((t & 63) >= off) inc += o;
    }
    // block-level: totals of preceding waves
    __shared__ float wtot[4];
    const int w = t >> 6, l = t & 63;
    if (l == 63) wtot[w] = inc;
    __syncthreads();
    float add = 0.f;
    #pragma unroll
    for (int k = 0; k < 3; k++)
        if (k < w) add += wtot[k];

    if (t < CH) {
        float run = (inc - s) + add + bias[d];
        const float wv[CHUNK] = {a.x, a.y, a.z, a.w, b.x, b.y, b.z, b.w};
        const int nbase = t * CHUNK;
        #pragma unroll
        for (int i = 0; i < CHUNK; i++) {
            T[(size_t)(nbase + i) * DD + d] = pack_bf16(run, wv[i]);
            run += wv[i];
        }
        if (t == CH - 1) {          // row NB: full prefix (rounding edge)
            T[(size_t)NB * DD + d] = pack_bf16(run, 0.f);
        }
    }
}

// ---------------------------------------------------------------------------
__global__ __launch_bounds__(256) void eval_kernel(const float* __restrict__ x,
                                                   const u4* __restrict__ T,
                                                   float* __restrict__ out) {
    const int tid  = threadIdx.x;
    const int lane = tid & 31;      // 32 lanes x 4 d's cover d=0..127
    const int slot = tid >> 5;      // 0..7
    const int base = blockIdx.x * 16;

    #pragma unroll
    for (int h = 0; h < 2; h++) {
        const int pair = base + slot + h * 8;
        const float pos = x[pair] + 1000.0f;
        const float fl  = floorf(pos);
        float frac = pos - fl;
        int fi = (int)fl;
        if (fi >= NB) { fi = NB; frac = 0.f; }
        if (fi < 0)   { fi = 0;  frac = 0.f; }

        // one 16B gather: 4 packed entries = d4..d4+3
        const u4 q = T[((size_t)fi * DD) / 4 + lane];

        f4 r;
        {
            float ct0 = __uint_as_float(q.x << 16);
            float wt0 = __uint_as_float(q.x & 0xffff0000u);
            float ct1 = __uint_as_float(q.y << 16);
            float wt1 = __uint_as_float(q.y & 0xffff0000u);
            float ct2 = __uint_as_float(q.z << 16);
            float wt2 = __uint_as_float(q.z & 0xffff0000u);
            float ct3 = __uint_as_float(q.w << 16);
            float wt3 = __uint_as_float(q.w & 0xffff0000u);
            r.x = fmaxf(fmaf(frac, wt0, ct0), 0.f);
            r.y = fmaxf(fmaf(frac, wt1, ct1), 0.f);
            r.z = fmaxf(fmaf(frac, wt2, ct2), 0.f);
            r.w = fmaxf(fmaf(frac, wt3, ct3), 0.f);
        }

        __builtin_nontemporal_store(r, (f4*)(out + (size_t)pair * DD + lane * 4));
    }
}

extern "C" void kernel_launch(void* const* d_in, const int* in_sizes, int n_in,
                              void* d_out, int out_size, void* d_ws, size_t ws_size,
                              hipStream_t stream) {
    const float* x    = (const float*)d_in[0];   // [128, 512]
    const float* W    = (const float*)d_in[1];   // [128, 2000]
    const float* bias = (const float*)d_in[2];   // [128]
    float* out = (float*)d_out;                  // [128, 512, 128] f32

    u32* T = (u32*)d_ws;                         // (NB+1) x 128 x u32 ~1.02MB

    hipLaunchKernelGGL(build_kernel, dim3(DD), dim3(256), 0, stream, W, bias, T);
    hipLaunchKernelGGL(eval_kernel, dim3(NPAIR / 16), dim3(256), 0, stream,
                       x, (const u4*)T, out);
}

// Round 7
// 16.609 us; speedup vs baseline: 8.7970x; 1.0684x over previous
//
#include <hip/hip_runtime.h>

// y[b,f,d] = relu( prefixW[d, fi] + frac * W[d, fi] + bias[d] ),
//   fi = floor(x+1000), frac = (x+1000) - fi.   B=128, F=512, D=128, NB=2000.
//
// Packed bf16 table, TILED layout:
//   T[tile][n][dw]  (tile = d>>4, dw = d&15),  u32 = { bf16(Wt)<<16 | bf16(Ct) }
//   Ct = sum_{k<n} W[d,k] + bias[d]  (bias folded),  Wt = W[d,n].
//   Row NB=2000 holds the full sum (pos==2000.0 float-rounding edge), Wt=0.
// Why tiled: a 64B line = 16 adjacent d's of one row n. Build blocks are
// swizzled (d = (bid&7)*16 + (bid>>3)) so all 16 d-columns of a tile are
// written by blocks with equal bid%8 -> same XCD -> full-line dirty in ONE
// L2, single writeback (kills the 16x partial-line write amplification of
// the flat [n][d] layout).
//
// K1 build: 128 blocks (one per swizzled d) x 256 thr; thread c sums its
//           8-bin chunk, block scan (wave shfl + LDS wave totals), emits.
// K2 eval : 4096 blocks x 256 thr, 16 pairs/block; per pair 32 lanes read
//           8 tiles x 64B (4 lanes per line); nontemporal f4 out stores.

#define NB    2000
#define DD    128
#define CHUNK 8
#define CH    250            // CH*CHUNK == NB
#define NPAIR (128 * 512)
#define TROW  (NB + 1)       // rows per tile

typedef float f4 __attribute__((ext_vector_type(4)));
typedef unsigned int u32;
typedef u32 u4 __attribute__((ext_vector_type(4)));

__device__ __forceinline__ u32 pack_bf16(float ct, float wt) {
    u32 cb = (__float_as_uint(ct) + 0x8000u) >> 16;          // RN bf16, low
    u32 wb = (__float_as_uint(wt) + 0x8000u) & 0xffff0000u;  // RN bf16, high
    return wb | cb;
}

// ---------------------------------------------------------------------------
__global__ __launch_bounds__(256) void build_kernel(const float* __restrict__ W,
                                                    const float* __restrict__ bias,
                                                    u32* __restrict__ T) {
    const int bid = blockIdx.x;            // 0..127
    const int d   = (bid & 7) * 16 + (bid >> 3);   // XCD-coherent tile mapping
    const int t   = threadIdx.x;           // chunk id; 0..249 active

    f4 a = {0.f, 0.f, 0.f, 0.f}, b = {0.f, 0.f, 0.f, 0.f};
    float s = 0.f;
    if (t < CH) {
        const f4* p = (const f4*)(W + (size_t)d * NB + t * CHUNK);
        a = p[0]; b = p[1];
        s = ((a.x + a.y) + (a.z + a.w)) + ((b.x + b.y) + (b.z + b.w));
    }

    // wave-level inclusive scan
    float inc = s;
    #pragma unroll
    for (int off = 1; off < 64; off <<= 1) {
        float o = __shfl_up(inc, off);
        if ((t & 63) >= off) inc += o;
    }
    // block-level: totals of preceding waves
    __shared__ float wtot[4];
    const int w = t >> 6, l = t & 63;
    if (l == 63) wtot[w] = inc;
    __syncthreads();
    float add = 0.f;
    #pragma unroll
    for (int k = 0; k < 3; k++)
        if (k < w) add += wtot[k];

    if (t < CH) {
        float run = (inc - s) + add + bias[d];
        const float wv[CHUNK] = {a.x, a.y, a.z, a.w, b.x, b.y, b.z, b.w};
        // tiled destination: T[d>>4][n][d&15]
        u32* col = T + (size_t)(d >> 4) * TROW * 16 + (d & 15);
        const int nbase = t * CHUNK;
        #pragma unroll
        for (int i = 0; i < CHUNK; i++) {
            col[(size_t)(nbase + i) * 16] = pack_bf16(run, wv[i]);
            run += wv[i];
        }
        if (t == CH - 1) {          // row NB: full prefix (rounding edge)
            col[(size_t)NB * 16] = pack_bf16(run, 0.f);
        }
    }
}

// ---------------------------------------------------------------------------
__global__ __launch_bounds__(256) void eval_kernel(const float* __restrict__ x,
                                                   const u4* __restrict__ T4,
                                                   float* __restrict__ out) {
    const int tid  = threadIdx.x;
    const int lane = tid & 31;      // 32 lanes x 4 d's cover d=0..127
    const int slot = tid >> 5;      // 0..7
    const int base = blockIdx.x * 16;
    // lane's tile and within-line quad: d4 = lane*4
    const int tile = lane >> 2;             // d4 >> 4
    const int quad = lane & 3;              // (d4 & 15) / 4
    const int tbase = tile * (TROW * 4) + quad;   // u4 units

    #pragma unroll
    for (int h = 0; h < 2; h++) {
        const int pair = base + slot + h * 8;
        const float pos = x[pair] + 1000.0f;
        const float fl  = floorf(pos);
        float frac = pos - fl;
        int fi = (int)fl;
        if (fi >= NB) { fi = NB; frac = 0.f; }
        if (fi < 0)   { fi = 0;  frac = 0.f; }

        // one 16B gather: 4 packed entries = d4..d4+3 of row fi in this tile
        const u4 q = T4[tbase + fi * 4];

        f4 r;
        {
            float ct0 = __uint_as_float(q.x << 16);
            float wt0 = __uint_as_float(q.x & 0xffff0000u);
            float ct1 = __uint_as_float(q.y << 16);
            float wt1 = __uint_as_float(q.y & 0xffff0000u);
            float ct2 = __uint_as_float(q.z << 16);
            float wt2 = __uint_as_float(q.z & 0xffff0000u);
            float ct3 = __uint_as_float(q.w << 16);
            float wt3 = __uint_as_float(q.w & 0xffff0000u);
            r.x = fmaxf(fmaf(frac, wt0, ct0), 0.f);
            r.y = fmaxf(fmaf(frac, wt1, ct1), 0.f);
            r.z = fmaxf(fmaf(frac, wt2, ct2), 0.f);
            r.w = fmaxf(fmaf(frac, wt3, ct3), 0.f);
        }

        __builtin_nontemporal_store(r, (f4*)(out + (size_t)pair * DD + lane * 4));
    }
}

extern "C" void kernel_launch(void* const* d_in, const int* in_sizes, int n_in,
                              void* d_out, int out_size, void* d_ws, size_t ws_size,
                              hipStream_t stream) {
    const float* x    = (const float*)d_in[0];   // [128, 512]
    const float* W    = (const float*)d_in[1];   // [128, 2000]
    const float* bias = (const float*)d_in[2];   // [128]
    float* out = (float*)d_out;                  // [128, 512, 128] f32

    u32* T = (u32*)d_ws;                         // 8 tiles x 2001 x 16 u32 ~1.02MB

    hipLaunchKernelGGL(build_kernel, dim3(DD), dim3(256), 0, stream, W, bias, T);
    hipLaunchKernelGGL(eval_kernel, dim3(NPAIR / 16), dim3(256), 0, stream,
                       x, (const u4*)T, out);
}